// Round 15
// baseline (182.178 us; speedup 1.0000x reference)
//
#include <hip/hip_runtime.h>
#include <hip/hip_bf16.h>
#include <stdint.h>

typedef short bf16x8 __attribute__((ext_vector_type(8)));
typedef short bf16x4 __attribute__((ext_vector_type(4)));
typedef float f32x4 __attribute__((ext_vector_type(4)));

#define HD 64
#define NH 16
#define SEQ 2048
#define BATCH 2
#define DM 1024
#define TOK (BATCH * SEQ)

__device__ __forceinline__ unsigned short f2bf(float f) {
    union { float f; unsigned u; } a; a.f = f;
    unsigned r = a.u + 0x7fffu + ((a.u >> 16) & 1u);
    return (unsigned short)(r >> 16);
}
__device__ __forceinline__ float bf2f(unsigned short u) {
    union { unsigned u; float f; } a; a.u = ((unsigned)u) << 16;
    return a.f;
}

// HW-packed 2xf32 -> 2xbf16 (v_cvt_pk_bf16_f32 on gfx950; one VALU op).
__device__ __forceinline__ unsigned pkbf16(float a, float b) {
    union { __hip_bfloat162 h; unsigned u; } cv;
    cv.h = __float22bfloat162_rn(make_float2(a, b));
    return cv.u;
}

__device__ __forceinline__ float fexp2(float x) {
#if __has_builtin(__builtin_amdgcn_exp2f)
    return __builtin_amdgcn_exp2f(x);
#else
    return exp2f(x);
#endif
}
__device__ __forceinline__ float frcp(float x) {
#if __has_builtin(__builtin_amdgcn_rcpf)
    return __builtin_amdgcn_rcpf(x);
#else
    return 1.0f / x;
#endif
}

// 16x16x16 bf16 MFMA (2-VGPR A/B frags), gfx90a-era builtin carried on gfx950.
// Device-compile guard: host pass lacks amdgcn MFMA builtins (R10 lesson).
__device__ __forceinline__ f32x4 mfma16(bf16x4 a, bf16x4 b, f32x4 c) {
#if defined(__HIP_DEVICE_COMPILE__)
    return __builtin_amdgcn_mfma_f32_16x16x16bf16_1k(a, b, c, 0, 0, 0);
#else
    (void)a; (void)b;
    return c;
#endif
}

// Direct global->LDS 16B DMA (m97). LDS dst is wave-uniform base + lane*16.
__device__ __forceinline__ void gld_lds16(const unsigned short* g, unsigned short* l) {
#if __has_builtin(__builtin_amdgcn_global_load_lds)
    __builtin_amdgcn_global_load_lds(
        (const __attribute__((address_space(1))) unsigned int*)g,
        (__attribute__((address_space(3))) unsigned int*)l, 16, 0, 0);
#else
    *(bf16x8*)l = *(const bf16x8*)g;
#endif
}

// ---------------- merged prep: cvt(x) + transpose-cvt(Wqkv) + transpose-cvt(Wout) ----
// R23: 64x64 tiles, float4 loads, LDS f32[64][65] (both sides 2-way/free),
// cvt_pk packing, ushort4 stores = 128B contiguous per n-row.
__global__ void __launch_bounds__(256) k_prep(const float* __restrict__ x,
                                              unsigned short* __restrict__ xb,
                                              const float* __restrict__ wqkv,
                                              unsigned short* __restrict__ wqkvt,
                                              const float* __restrict__ wout,
                                              unsigned short* __restrict__ woutt) {
    int bid = blockIdx.x;
    int tid = threadIdx.x;
    if (bid < 4096) {
        int i = (bid * 256 + tid) * 4;
        float4 v = *(const float4*)(x + i);
        union { ushort4 v; unsigned short s[4]; } o;
        o.s[0] = f2bf(v.x); o.s[1] = f2bf(v.y); o.s[2] = f2bf(v.z); o.s[3] = f2bf(v.w);
        *(ushort4*)(xb + i) = o.v;
        return;
    }
    const float* W; unsigned short* Wt; int N, t;
    if (bid < 4864) { W = wqkv; Wt = wqkvt; N = 3 * DM; t = bid - 4096; }
    else            { W = wout; Wt = woutt; N = DM;     t = bid - 4864; }
    int ntx = N >> 6;
    int bx = t % ntx, by = t / ntx;
    int n0 = bx * 64, k0 = by * 64;
    __shared__ float tile[64][65];
    for (int it = 0; it < 4; ++it) {
        int idx = it * 256 + tid;          // 1024 float4 slots: 64 rows x 16
        int r = idx >> 4, c4 = idx & 15;
        float4 v = *(const float4*)(W + (size_t)(k0 + r) * N + n0 + c4 * 4);
        tile[r][c4 * 4 + 0] = v.x;
        tile[r][c4 * 4 + 1] = v.y;
        tile[r][c4 * 4 + 2] = v.z;
        tile[r][c4 * 4 + 3] = v.w;
    }
    __syncthreads();
    for (int it = 0; it < 4; ++it) {
        int nn = it * 16 + (tid >> 4);     // output row (n)
        int kk = (tid & 15) * 4;           // 4 consecutive k
        union { ushort4 v; unsigned u[2]; } pk;
        pk.u[0] = pkbf16(tile[kk + 0][nn], tile[kk + 1][nn]);
        pk.u[1] = pkbf16(tile[kk + 2][nn], tile[kk + 3][nn]);
        *(ushort4*)(Wt + (size_t)(n0 + nn) * DM + k0 + kk) = pk.v;
    }
}

#define BKK 32

// ---------------- QKV GEMM: 128x128 tile, B^T input (R8-exact, FINAL) --------
// Proven 2-phase dbuf at 3 blocks/CU (43.6-44.0us, 22% MfmaUtil). Session
// evidence: structural rewrites all lost 16-24us (R2 ring 66.9, R6 reshape
// 70.2, R7 8-phase 62.8); chsw frag-read swizzle is a no-op (R9: conflict
// counter byte-identical -> conflicts are DMA-write-side and hidden); rope/V
// epilogue fusions cost VGPR/occupancy (R3/R4). At K=1024/grid-768 the
// implicit inter-block overlap (m114) is the binding mechanism and this
// config maximizes it. XCD-chunked bijective swizzle: FETCH 40->28.7MB.
__global__ void __launch_bounds__(256) k_gemm_qkv(const unsigned short* __restrict__ A,
                                                  const unsigned short* __restrict__ Bt,
                                                  unsigned short* __restrict__ qbuf,
                                                  unsigned short* __restrict__ kbuf,
                                                  unsigned short* __restrict__ vt) {
    constexpr int K = DM;
    __shared__ unsigned short As0[128 * BKK];
    __shared__ unsigned short As1[128 * BKK];
    __shared__ unsigned short Bs0[128 * BKK];
    __shared__ unsigned short Bs1[128 * BKK];
    int tid = threadIdx.x;
    int lane = tid & 63, wave = tid >> 6;
    int lin = (int)blockIdx.x + (int)blockIdx.y * 24;
    int nl = (lin & 7) * 96 + (lin >> 3);
    int bx = nl % 24, by = nl / 24;
    int row0 = by * 128;
    int col0 = bx * 128;
    int wm = (wave >> 1) * 64, wn = (wave & 1) * 64;
    int fr = lane & 15;
    int quad = lane >> 4;

    f32x4 zero4 = {0.f, 0.f, 0.f, 0.f};
    f32x4 acc[4][4];
    for (int i = 0; i < 4; ++i)
        for (int j = 0; j < 4; ++j) acc[i][j] = zero4;

    auto stage = [&](unsigned short* Ad, unsigned short* Bd, int k0) {
        for (int i = 0; i < 2; ++i) {
            int s2 = i * 256 + tid;
            int r = s2 >> 2, kc = s2 & 3;
            int kk = (kc ^ (r & 3)) * 8;
            gld_lds16(A + (size_t)(row0 + r) * K + k0 + kk, Ad + (i * 256 + wave * 64) * 8);
            gld_lds16(Bt + (size_t)(col0 + r) * K + k0 + kk, Bd + (i * 256 + wave * 64) * 8);
        }
    };
    auto compute = [&](const unsigned short* Al, const unsigned short* Bl) {
        bf16x8 af[4], bf[4];
        for (int i = 0; i < 4; ++i) {
            int rr = wm + i * 16 + fr;
            af[i] = *(const bf16x8*)&Al[rr * BKK + ((quad ^ (rr & 3)) * 8)];
        }
        for (int j = 0; j < 4; ++j) {
            int rr = wn + j * 16 + fr;
            bf[j] = *(const bf16x8*)&Bl[rr * BKK + ((quad ^ (rr & 3)) * 8)];
        }
        for (int i = 0; i < 4; ++i)
            for (int j = 0; j < 4; ++j)
                acc[i][j] = __builtin_amdgcn_mfma_f32_16x16x32_bf16(af[i], bf[j], acc[i][j], 0, 0, 0);
    };

    stage(As0, Bs0, 0);
    __syncthreads();  // tile 0 DMA drained
    for (int k0 = 0; k0 < K; k0 += 2 * BKK) {  // K multiple of 64
        if (k0 + BKK < K) stage(As1, Bs1, k0 + BKK);
        compute(As0, Bs0);
        __syncthreads();
        if (k0 + 2 * BKK < K) stage(As0, Bs0, k0 + 2 * BKK);
        compute(As1, Bs1);
        __syncthreads();
    }

    int rq = (lane >> 4) * 4;
    int cq = lane & 15;
    for (int i = 0; i < 4; ++i)
        for (int j = 0; j < 4; ++j)
            for (int reg = 0; reg < 4; ++reg) {
                int row = row0 + wm + i * 16 + rq + reg;  // token index
                int col = col0 + wn + j * 16 + cq;        // output col
                float v = acc[i][j][reg];
                int which = col >> 10;
                int hc = col & 1023;
                int h = hc >> 6, d = hc & 63;
                int b = row >> 11, s = row & (SEQ - 1);
                int bh = b * NH + h;
                unsigned short bv = f2bf(v);
                if (which == 0)      qbuf[((size_t)bh * SEQ + s) * HD + d] = bv;
                else if (which == 1) kbuf[((size_t)bh * SEQ + s) * HD + d] = bv;
                else                 vt[((size_t)bh * HD + d) * SEQ + s] = bv;
            }
}

// ---------------- OUT GEMM: 128x64 tile, 2-wave blocks (R8-exact, FINAL) -----
// 512 blocks = 2/CU (grid-limited), 24KB LDS. XCD-chunked swizzle.
__global__ void __launch_bounds__(128) k_gemm_out(const unsigned short* __restrict__ A,
                                                  const unsigned short* __restrict__ Bt,
                                                  float* __restrict__ C) {
    constexpr int K = DM;
    __shared__ unsigned short As0[128 * BKK];
    __shared__ unsigned short As1[128 * BKK];
    __shared__ unsigned short Bs0[64 * BKK];
    __shared__ unsigned short Bs1[64 * BKK];
    int tid = threadIdx.x;              // 0..127
    int lane = tid & 63, wave = tid >> 6;  // 2 waves
    int lin = (int)blockIdx.x + (int)blockIdx.y * 16;   // grid (16,32)
    int nl = (lin & 7) * 64 + (lin >> 3);
    int bx = nl & 15, by = nl >> 4;
    int row0 = by * 128, col0 = bx * 64;
    int wm = wave * 64;                 // wave owns 64 M-rows x full 64 N
    int fr = lane & 15, quad = lane >> 4;

    f32x4 zero4 = {0.f, 0.f, 0.f, 0.f};
    f32x4 acc[4][4];
    for (int i = 0; i < 4; ++i)
        for (int j = 0; j < 4; ++j) acc[i][j] = zero4;

    auto stage = [&](unsigned short* Ad, unsigned short* Bd, int k0) {
        for (int i = 0; i < 4; ++i) {
            int idx = i * 128 + tid;
            int r = idx >> 2, kc = idx & 3;
            int kk = (kc ^ (r & 3)) * 8;
            gld_lds16(A + (size_t)(row0 + r) * K + k0 + kk, Ad + (i * 128 + wave * 64) * 8);
        }
        for (int i = 0; i < 2; ++i) {
            int idx = i * 128 + tid;
            int r = idx >> 2, kc = idx & 3;
            int kk = (kc ^ (r & 3)) * 8;
            gld_lds16(Bt + (size_t)(col0 + r) * K + k0 + kk, Bd + (i * 128 + wave * 64) * 8);
        }
    };
    auto compute = [&](const unsigned short* Al, const unsigned short* Bl) {
        bf16x8 af[4], bfr[4];
        for (int i = 0; i < 4; ++i) {
            int rr = wm + i * 16 + fr;
            af[i] = *(const bf16x8*)&Al[rr * BKK + ((quad ^ (rr & 3)) * 8)];
        }
        for (int j = 0; j < 4; ++j) {
            int rr = j * 16 + fr;
            bfr[j] = *(const bf16x8*)&Bl[rr * BKK + ((quad ^ (rr & 3)) * 8)];
        }
        for (int i = 0; i < 4; ++i)
            for (int j = 0; j < 4; ++j)
                acc[i][j] = __builtin_amdgcn_mfma_f32_16x16x32_bf16(af[i], bfr[j], acc[i][j], 0, 0, 0);
    };

    stage(As0, Bs0, 0);
    __syncthreads();  // tile 0 DMA drained
    for (int k0 = 0; k0 < K; k0 += 2 * BKK) {
        if (k0 + BKK < K) stage(As1, Bs1, k0 + BKK);
        compute(As0, Bs0);
        __syncthreads();
        if (k0 + 2 * BKK < K) stage(As0, Bs0, k0 + 2 * BKK);
        compute(As1, Bs1);
        __syncthreads();
    }

    int rq = quad * 4;
    int cq = fr;
    for (int i = 0; i < 4; ++i)
        for (int j = 0; j < 4; ++j)
            for (int reg = 0; reg < 4; ++reg) {
                int row = row0 + wm + i * 16 + rq + reg;
                int col = col0 + j * 16 + cq;
                C[(size_t)row * DM + col] = acc[i][j][reg];
            }
}

// ---------------- RoPE in place on K only (R28) ----------------
// Q-rope lives in k_attn's Q-load prologue. K rows are staged by many attn
// blocks each, so K-rope stays standalone. 2048 blocks.
__global__ void k_rope(unsigned short* __restrict__ kbuf,
                       const float* __restrict__ cosb, const float* __restrict__ sinb) {
    int t = blockIdx.x * 256 + threadIdx.x;
    int c = t & 7;
    int row = t >> 3;                  // 0..65535
    unsigned short* p = kbuf + (size_t)row * HD + c * 8;
    int s = row & (SEQ - 1);
    const float* cs = cosb + s * 32 + c * 4;
    const float* sn = sinb + s * 32 + c * 4;
    bf16x8 v = *(const bf16x8*)p;
    bf16x8 o;
    for (int i = 0; i < 4; ++i) {
        float x1 = bf2f((unsigned short)v[2 * i]);
        float x2 = bf2f((unsigned short)v[2 * i + 1]);
        float cc = cs[i], ss = sn[i];
        o[2 * i]     = (short)f2bf(x1 * cc - x2 * ss);
        o[2 * i + 1] = (short)f2bf(x1 * ss + x2 * cc);
    }
    *(bf16x8*)p = o;
}

// ---------------- Flash attention: causal work-paired, 4-wave blocks ----------
// R29 (kept): 4 waves/block, each wave owns complementary q16-tiles (4p+w,
// 127-4p-w); each 16KB K/V staging serves 8 query sets. 2 blocks/CU.
// R30: XCD-chunked block remap (512 % 8 == 0). The 16 x-blocks of one bh all
// read the SAME 512KB of K/V; linear dispatch round-robins them across XCDs
// so every XCD's L2 fills K/V for ~all 32 bh (8x redundant L3 re-fetch).
// Remap nl=(lin&7)*64+(lin>>3): each XCD owns 4 consecutive bh x all 16
// x-blocks -> its L2 holds 4 bh of K/V (2MB, fits 4MB L2) fetched once (T1:
// same-bh blocks share operand panels exactly). Pure bijective index remap.
// Q-rope + scale in-register at Q-load (R28). NOTE (R11): no setprio --
// barrier-lockstep waves (m190 regime).
__global__ void __launch_bounds__(256, 2) k_attn(const unsigned short* __restrict__ qbuf,
                                                 const unsigned short* __restrict__ kbuf,
                                                 const unsigned short* __restrict__ vt,
                                                 const float* __restrict__ cosb,
                                                 const float* __restrict__ sinb,
                                                 unsigned short* __restrict__ obuf) {
    __shared__ unsigned short Ks0[64 * 64];
    __shared__ unsigned short Ks1[64 * 64];
    __shared__ unsigned short Vs0[64 * 64];
    __shared__ unsigned short Vs1[64 * 64];

    int tid = threadIdx.x;             // 0..255
    int lane = tid & 63, wave = tid >> 6;  // wave 0..3
    // R30 XCD-chunked remap: lin = y*16+x (x fastest in dispatch order).
    int lin = (int)blockIdx.y * 16 + (int)blockIdx.x;   // 0..511
    int nl = (lin & 7) * 64 + (lin >> 3);
    int bxp = nl & 15;                 // logical x-block (pair selector)
    int bh = nl >> 4;                  // logical batch*head
    int b = bh >> 4, h = bh & 15;
    int p = (bxp + bh) & 15;           // swizzled pair index
    int fr = lane & 15, quad = lane >> 4, sw = fr & 7;
    // This wave's two 16-query sets: low tile (4p+w), high tile (127-4p-w).
    int Qb0 = (4 * p + wave) * 16;
    int Qb1 = (127 - 4 * p - wave) * 16;
    // Block-uniform trip count: covers the widest causal range in the block.
    int KT = ((127 - 4 * p) >> 2) + 1;

    const unsigned short* Qb = qbuf + (size_t)bh * SEQ * HD;
    const unsigned short* Kb = kbuf + (size_t)bh * SEQ * HD;
    const unsigned short* Vb = vt + (size_t)bh * HD * SEQ;

    // Q B-frags, 2 sets of 16 queries. RoPE + 1/sqrt(64)*log2(e) pre-scale
    // applied in-register (R28); pair idx = d/2, frag covers d = dbase..+7.
    auto ropeQ = [&](bf16x8 v, int qrow, int dbase) -> bf16x8 {
        const float sc = 0.125f * 1.44269504f;
        const float* cs = cosb + (size_t)qrow * 32 + (dbase >> 1);
        const float* sn = sinb + (size_t)qrow * 32 + (dbase >> 1);
        bf16x8 o;
        for (int i = 0; i < 4; ++i) {
            float x1 = bf2f((unsigned short)v[2 * i]);
            float x2 = bf2f((unsigned short)v[2 * i + 1]);
            float cc = cs[i], ss = sn[i];
            o[2 * i]     = (short)f2bf((x1 * cc - x2 * ss) * sc);
            o[2 * i + 1] = (short)f2bf((x1 * ss + x2 * cc) * sc);
        }
        return o;
    };
    bf16x8 qf[2][2];
    for (int s = 0; s < 2; ++s) {
        int qrow = (s ? Qb1 : Qb0) + fr;   // within [0, SEQ)
        qf[s][0] = ropeQ(*(const bf16x8*)(Qb + (size_t)qrow * HD + quad * 8), qrow, quad * 8);
        qf[s][1] = ropeQ(*(const bf16x8*)(Qb + (size_t)qrow * HD + 32 + quad * 8), qrow, 32 + quad * 8);
    }

    f32x4 zero4 = {0.f, 0.f, 0.f, 0.f};
    f32x4 o[2][4];
    for (int s = 0; s < 2; ++s)
        for (int j = 0; j < 4; ++j) o[s][j] = zero4;
    float l[2] = {0.f, 0.f};

    // DMA staging (256 threads): 512 16B-slots per K tile -> 2 issues each.
    auto stage = [&](int kb, unsigned short* Kd, unsigned short* Vd) {
        for (int a = 0; a < 2; ++a) {
            int idx = a * 256 + tid;
            int r = idx >> 3;
            int lg = (idx & 7) ^ (r & 7);
            gld_lds16(Kb + (size_t)(kb + r) * HD + lg * 8, Kd + (a * 256 + wave * 64) * 8);
            gld_lds16(Vb + (size_t)r * SEQ + kb + lg * 8, Vd + (a * 256 + wave * 64) * 8);
        }
    };

    auto compute = [&](int kt, const unsigned short* Kd, const unsigned short* Vd) {
        int kb = kt * 64;
        // ---- fragments once per tile, shared by both query sets ----
        bf16x8 ka[4], kc[4];
        for (int g = 0; g < 4; ++g) {
            int r = g * 16 + fr;
            ka[g] = *(const bf16x8*)&Kd[r * 64 + ((quad ^ sw) * 8)];
            kc[g] = *(const bf16x8*)&Kd[r * 64 + (((quad + 4) ^ sw) * 8)];
        }
        bf16x4 vf[4][4];
        for (int g = 0; g < 4; ++g)
            for (int db = 0; db < 4; ++db) {
                int d = db * 16 + fr;
                int pg = ((2 * g + (quad >> 1)) ^ sw) * 8 + (quad & 1) * 4;
                vf[g][db] = *(const bf16x4*)&Vd[d * 64 + pg];
            }
        // ---- two 16-query sets through QK -> softmax -> PV ----
        for (int s = 0; s < 2; ++s) {
            int Qs = s ? Qb1 : Qb0;
            if (kb > Qs + 15) continue;  // set fully below this K-tile: skip (wave-uniform)
            f32x4 sg[4];
            for (int g = 0; g < 4; ++g) {
                f32x4 z = zero4;
                z = __builtin_amdgcn_mfma_f32_16x16x32_bf16(ka[g], qf[s][0], z, 0, 0, 0);
                z = __builtin_amdgcn_mfma_f32_16x16x32_bf16(kc[g], qf[s][1], z, 0, 0, 0);
                sg[g] = z;
            }
            if (kb + 63 > Qs) {  // any key could exceed the smallest query
                int q = Qs + fr;
                for (int g = 0; g < 4; ++g)
                    for (int reg = 0; reg < 4; ++reg)
                        if (kb + g * 16 + quad * 4 + reg > q) sg[g][reg] = -1e30f;
            }
            bf16x4 pf[4];
            for (int g = 0; g < 4; ++g) {
                float p0 = fexp2(sg[g][0]);
                float p1 = fexp2(sg[g][1]);
                float p2 = fexp2(sg[g][2]);
                float p3 = fexp2(sg[g][3]);
                l[s] += (p0 + p1) + (p2 + p3);
                union { bf16x4 v; unsigned u[2]; } pc;
                pc.u[0] = pkbf16(p0, p1);
                pc.u[1] = pkbf16(p2, p3);
                pf[g] = pc.v;
            }
            for (int g = 0; g < 4; ++g)
                for (int db = 0; db < 4; ++db)
                    o[s][db] = mfma16(pf[g], vf[g][db], o[s][db]);
        }
    };

    stage(0, Ks0, Vs0);
    __syncthreads();  // tile 0 DMA drained
    for (int kt = 0; kt < KT; kt += 2) {
        if (kt + 1 < KT) stage((kt + 1) * 64, Ks1, Vs1);
        compute(kt, Ks0, Vs0);
        __syncthreads();  // Ks0/Vs0 readers done; Ks1/Vs1 DMA drained
        if (kt + 1 < KT) {
            if (kt + 2 < KT) stage((kt + 2) * 64, Ks0, Vs0);
            compute(kt + 1, Ks1, Vs1);
            __syncthreads();
        }
    }

    // ---- per set: finish l across quads; store ----
    for (int s = 0; s < 2; ++s) {
        float ll = l[s];
        ll += __shfl_xor(ll, 16);
        ll += __shfl_xor(ll, 32);
        float linv[4];
        for (int reg = 0; reg < 4; ++reg)
            linv[reg] = frcp(__shfl(ll, quad * 4 + reg));
        int Qs = s ? Qb1 : Qb0;
        for (int db = 0; db < 4; ++db)
            for (int reg = 0; reg < 4; ++reg) {
                int row = Qs + quad * 4 + reg;
                int d = db * 16 + fr;
                obuf[((size_t)(b * SEQ + row)) * DM + h * HD + d] = f2bf(o[s][db][reg] * linv[reg]);
            }
    }
}

extern "C" void kernel_launch(void* const* d_in, const int* in_sizes, int n_in,
                              void* d_out, int out_size, void* d_ws, size_t ws_size,
                              hipStream_t stream) {
    const float* x    = (const float*)d_in[0];
    const float* rc   = (const float*)d_in[1];
    const float* rs   = (const float*)d_in[2];
    const float* wqkv = (const float*)d_in[3];
    const float* wout = (const float*)d_in[4];
    float* out = (float*)d_out;

    char* ws = (char*)d_ws;
    size_t off = 0;
    auto alloc = [&](size_t bytes) {
        char* p = ws + off;
        off += (bytes + 255) & ~(size_t)255;
        return p;
    };
    unsigned short* xb    = (unsigned short*)alloc((size_t)TOK * DM * 2);
    unsigned short* wqkvt = (unsigned short*)alloc((size_t)3 * DM * DM * 2);
    unsigned short* woutt = (unsigned short*)alloc((size_t)DM * DM * 2);
    unsigned short* qbuf  = (unsigned short*)alloc((size_t)BATCH * NH * SEQ * HD * 2);
    unsigned short* kbuf  = (unsigned short*)alloc((size_t)BATCH * NH * SEQ * HD * 2);
    unsigned short* vtb   = (unsigned short*)alloc((size_t)BATCH * NH * SEQ * HD * 2);
    unsigned short* obuf  = (unsigned short*)alloc((size_t)TOK * DM * 2);

    k_prep<<<5120, 256, 0, stream>>>(x, xb, wqkv, wqkvt, wout, woutt);
    k_gemm_qkv<<<dim3(3 * DM / 128, TOK / 128), 256, 0, stream>>>(xb, wqkvt, qbuf, kbuf, vtb);
    k_rope<<<2048, 256, 0, stream>>>(kbuf, rc, rs);
    k_attn<<<dim3(SEQ / 128, BATCH * NH), 256, 0, stream>>>(qbuf, kbuf, vtb, rc, rs, obuf);
    k_gemm_out<<<dim3(DM / 64, TOK / 128), 128, 0, stream>>>(obuf, woutt, out);
}

// Round 16
// 179.683 us; speedup vs baseline: 1.0139x; 1.0139x over previous
//
#include <hip/hip_runtime.h>
#include <hip/hip_bf16.h>
#include <stdint.h>

typedef short bf16x8 __attribute__((ext_vector_type(8)));
typedef short bf16x4 __attribute__((ext_vector_type(4)));
typedef float f32x4 __attribute__((ext_vector_type(4)));

#define HD 64
#define NH 16
#define SEQ 2048
#define BATCH 2
#define DM 1024
#define TOK (BATCH * SEQ)

__device__ __forceinline__ unsigned short f2bf(float f) {
    union { float f; unsigned u; } a; a.f = f;
    unsigned r = a.u + 0x7fffu + ((a.u >> 16) & 1u);
    return (unsigned short)(r >> 16);
}
__device__ __forceinline__ float bf2f(unsigned short u) {
    union { unsigned u; float f; } a; a.u = ((unsigned)u) << 16;
    return a.f;
}

// HW-packed 2xf32 -> 2xbf16 (v_cvt_pk_bf16_f32 on gfx950; one VALU op).
__device__ __forceinline__ unsigned pkbf16(float a, float b) {
    union { __hip_bfloat162 h; unsigned u; } cv;
    cv.h = __float22bfloat162_rn(make_float2(a, b));
    return cv.u;
}

__device__ __forceinline__ float fexp2(float x) {
#if __has_builtin(__builtin_amdgcn_exp2f)
    return __builtin_amdgcn_exp2f(x);
#else
    return exp2f(x);
#endif
}
__device__ __forceinline__ float frcp(float x) {
#if __has_builtin(__builtin_amdgcn_rcpf)
    return __builtin_amdgcn_rcpf(x);
#else
    return 1.0f / x;
#endif
}

// 16x16x16 bf16 MFMA (2-VGPR A/B frags), gfx90a-era builtin carried on gfx950.
// Device-compile guard: host pass lacks amdgcn MFMA builtins (R10 lesson).
__device__ __forceinline__ f32x4 mfma16(bf16x4 a, bf16x4 b, f32x4 c) {
#if defined(__HIP_DEVICE_COMPILE__)
    return __builtin_amdgcn_mfma_f32_16x16x16bf16_1k(a, b, c, 0, 0, 0);
#else
    (void)a; (void)b;
    return c;
#endif
}

// Direct global->LDS 16B DMA (m97). LDS dst is wave-uniform base + lane*16.
__device__ __forceinline__ void gld_lds16(const unsigned short* g, unsigned short* l) {
#if __has_builtin(__builtin_amdgcn_global_load_lds)
    __builtin_amdgcn_global_load_lds(
        (const __attribute__((address_space(1))) unsigned int*)g,
        (__attribute__((address_space(3))) unsigned int*)l, 16, 0, 0);
#else
    *(bf16x8*)l = *(const bf16x8*)g;
#endif
}

// ---------------- merged prep: cvt(x) + transpose-cvt(Wqkv) + transpose-cvt(Wout) ----
// R23: 64x64 tiles, float4 loads, LDS f32[64][65] (both sides 2-way/free),
// cvt_pk packing, ushort4 stores = 128B contiguous per n-row.
__global__ void __launch_bounds__(256) k_prep(const float* __restrict__ x,
                                              unsigned short* __restrict__ xb,
                                              const float* __restrict__ wqkv,
                                              unsigned short* __restrict__ wqkvt,
                                              const float* __restrict__ wout,
                                              unsigned short* __restrict__ woutt) {
    int bid = blockIdx.x;
    int tid = threadIdx.x;
    if (bid < 4096) {
        int i = (bid * 256 + tid) * 4;
        float4 v = *(const float4*)(x + i);
        union { ushort4 v; unsigned short s[4]; } o;
        o.s[0] = f2bf(v.x); o.s[1] = f2bf(v.y); o.s[2] = f2bf(v.z); o.s[3] = f2bf(v.w);
        *(ushort4*)(xb + i) = o.v;
        return;
    }
    const float* W; unsigned short* Wt; int N, t;
    if (bid < 4864) { W = wqkv; Wt = wqkvt; N = 3 * DM; t = bid - 4096; }
    else            { W = wout; Wt = woutt; N = DM;     t = bid - 4864; }
    int ntx = N >> 6;
    int bx = t % ntx, by = t / ntx;
    int n0 = bx * 64, k0 = by * 64;
    __shared__ float tile[64][65];
    for (int it = 0; it < 4; ++it) {
        int idx = it * 256 + tid;          // 1024 float4 slots: 64 rows x 16
        int r = idx >> 4, c4 = idx & 15;
        float4 v = *(const float4*)(W + (size_t)(k0 + r) * N + n0 + c4 * 4);
        tile[r][c4 * 4 + 0] = v.x;
        tile[r][c4 * 4 + 1] = v.y;
        tile[r][c4 * 4 + 2] = v.z;
        tile[r][c4 * 4 + 3] = v.w;
    }
    __syncthreads();
    for (int it = 0; it < 4; ++it) {
        int nn = it * 16 + (tid >> 4);     // output row (n)
        int kk = (tid & 15) * 4;           // 4 consecutive k
        union { ushort4 v; unsigned u[2]; } pk;
        pk.u[0] = pkbf16(tile[kk + 0][nn], tile[kk + 1][nn]);
        pk.u[1] = pkbf16(tile[kk + 2][nn], tile[kk + 3][nn]);
        *(ushort4*)(Wt + (size_t)(n0 + nn) * DM + k0 + kk) = pk.v;
    }
}

#define BKK 32

// ---------------- QKV GEMM: 128x128 tile, B^T input (R8-exact, FINAL) --------
// Proven 2-phase dbuf at 3 blocks/CU (43.6-44.0us, 22% MfmaUtil). Session
// evidence: structural rewrites all lost 16-24us (R2 ring 66.9, R6 reshape
// 70.2, R7 8-phase 62.8); chsw frag-read swizzle is a no-op (R9: conflict
// counter byte-identical -> conflicts are DMA-write-side and hidden); rope/V
// epilogue fusions cost VGPR/occupancy (R3/R4). At K=1024/grid-768 the
// implicit inter-block overlap (m114) is the binding mechanism and this
// config maximizes it. XCD-chunked bijective swizzle: FETCH 40->28.7MB.
__global__ void __launch_bounds__(256) k_gemm_qkv(const unsigned short* __restrict__ A,
                                                  const unsigned short* __restrict__ Bt,
                                                  unsigned short* __restrict__ qbuf,
                                                  unsigned short* __restrict__ kbuf,
                                                  unsigned short* __restrict__ vt) {
    constexpr int K = DM;
    __shared__ unsigned short As0[128 * BKK];
    __shared__ unsigned short As1[128 * BKK];
    __shared__ unsigned short Bs0[128 * BKK];
    __shared__ unsigned short Bs1[128 * BKK];
    int tid = threadIdx.x;
    int lane = tid & 63, wave = tid >> 6;
    int lin = (int)blockIdx.x + (int)blockIdx.y * 24;
    int nl = (lin & 7) * 96 + (lin >> 3);
    int bx = nl % 24, by = nl / 24;
    int row0 = by * 128;
    int col0 = bx * 128;
    int wm = (wave >> 1) * 64, wn = (wave & 1) * 64;
    int fr = lane & 15;
    int quad = lane >> 4;

    f32x4 zero4 = {0.f, 0.f, 0.f, 0.f};
    f32x4 acc[4][4];
    for (int i = 0; i < 4; ++i)
        for (int j = 0; j < 4; ++j) acc[i][j] = zero4;

    auto stage = [&](unsigned short* Ad, unsigned short* Bd, int k0) {
        for (int i = 0; i < 2; ++i) {
            int s2 = i * 256 + tid;
            int r = s2 >> 2, kc = s2 & 3;
            int kk = (kc ^ (r & 3)) * 8;
            gld_lds16(A + (size_t)(row0 + r) * K + k0 + kk, Ad + (i * 256 + wave * 64) * 8);
            gld_lds16(Bt + (size_t)(col0 + r) * K + k0 + kk, Bd + (i * 256 + wave * 64) * 8);
        }
    };
    auto compute = [&](const unsigned short* Al, const unsigned short* Bl) {
        bf16x8 af[4], bf[4];
        for (int i = 0; i < 4; ++i) {
            int rr = wm + i * 16 + fr;
            af[i] = *(const bf16x8*)&Al[rr * BKK + ((quad ^ (rr & 3)) * 8)];
        }
        for (int j = 0; j < 4; ++j) {
            int rr = wn + j * 16 + fr;
            bf[j] = *(const bf16x8*)&Bl[rr * BKK + ((quad ^ (rr & 3)) * 8)];
        }
        for (int i = 0; i < 4; ++i)
            for (int j = 0; j < 4; ++j)
                acc[i][j] = __builtin_amdgcn_mfma_f32_16x16x32_bf16(af[i], bf[j], acc[i][j], 0, 0, 0);
    };

    stage(As0, Bs0, 0);
    __syncthreads();  // tile 0 DMA drained
    for (int k0 = 0; k0 < K; k0 += 2 * BKK) {  // K multiple of 64
        if (k0 + BKK < K) stage(As1, Bs1, k0 + BKK);
        compute(As0, Bs0);
        __syncthreads();
        if (k0 + 2 * BKK < K) stage(As0, Bs0, k0 + 2 * BKK);
        compute(As1, Bs1);
        __syncthreads();
    }

    int rq = (lane >> 4) * 4;
    int cq = lane & 15;
    for (int i = 0; i < 4; ++i)
        for (int j = 0; j < 4; ++j)
            for (int reg = 0; reg < 4; ++reg) {
                int row = row0 + wm + i * 16 + rq + reg;  // token index
                int col = col0 + wn + j * 16 + cq;        // output col
                float v = acc[i][j][reg];
                int which = col >> 10;
                int hc = col & 1023;
                int h = hc >> 6, d = hc & 63;
                int b = row >> 11, s = row & (SEQ - 1);
                int bh = b * NH + h;
                unsigned short bv = f2bf(v);
                if (which == 0)      qbuf[((size_t)bh * SEQ + s) * HD + d] = bv;
                else if (which == 1) kbuf[((size_t)bh * SEQ + s) * HD + d] = bv;
                else                 vt[((size_t)bh * HD + d) * SEQ + s] = bv;
            }
}

// ---------------- OUT GEMM: 128x64 tile, 2-wave blocks (R8-exact, FINAL) -----
// 512 blocks = 2/CU (grid-limited), 24KB LDS. XCD-chunked swizzle.
__global__ void __launch_bounds__(128) k_gemm_out(const unsigned short* __restrict__ A,
                                                  const unsigned short* __restrict__ Bt,
                                                  float* __restrict__ C) {
    constexpr int K = DM;
    __shared__ unsigned short As0[128 * BKK];
    __shared__ unsigned short As1[128 * BKK];
    __shared__ unsigned short Bs0[64 * BKK];
    __shared__ unsigned short Bs1[64 * BKK];
    int tid = threadIdx.x;              // 0..127
    int lane = tid & 63, wave = tid >> 6;  // 2 waves
    int lin = (int)blockIdx.x + (int)blockIdx.y * 16;   // grid (16,32)
    int nl = (lin & 7) * 64 + (lin >> 3);
    int bx = nl & 15, by = nl >> 4;
    int row0 = by * 128, col0 = bx * 64;
    int wm = wave * 64;                 // wave owns 64 M-rows x full 64 N
    int fr = lane & 15, quad = lane >> 4;

    f32x4 zero4 = {0.f, 0.f, 0.f, 0.f};
    f32x4 acc[4][4];
    for (int i = 0; i < 4; ++i)
        for (int j = 0; j < 4; ++j) acc[i][j] = zero4;

    auto stage = [&](unsigned short* Ad, unsigned short* Bd, int k0) {
        for (int i = 0; i < 4; ++i) {
            int idx = i * 128 + tid;
            int r = idx >> 2, kc = idx & 3;
            int kk = (kc ^ (r & 3)) * 8;
            gld_lds16(A + (size_t)(row0 + r) * K + k0 + kk, Ad + (i * 128 + wave * 64) * 8);
        }
        for (int i = 0; i < 2; ++i) {
            int idx = i * 128 + tid;
            int r = idx >> 2, kc = idx & 3;
            int kk = (kc ^ (r & 3)) * 8;
            gld_lds16(Bt + (size_t)(col0 + r) * K + k0 + kk, Bd + (i * 128 + wave * 64) * 8);
        }
    };
    auto compute = [&](const unsigned short* Al, const unsigned short* Bl) {
        bf16x8 af[4], bfr[4];
        for (int i = 0; i < 4; ++i) {
            int rr = wm + i * 16 + fr;
            af[i] = *(const bf16x8*)&Al[rr * BKK + ((quad ^ (rr & 3)) * 8)];
        }
        for (int j = 0; j < 4; ++j) {
            int rr = j * 16 + fr;
            bfr[j] = *(const bf16x8*)&Bl[rr * BKK + ((quad ^ (rr & 3)) * 8)];
        }
        for (int i = 0; i < 4; ++i)
            for (int j = 0; j < 4; ++j)
                acc[i][j] = __builtin_amdgcn_mfma_f32_16x16x32_bf16(af[i], bfr[j], acc[i][j], 0, 0, 0);
    };

    stage(As0, Bs0, 0);
    __syncthreads();  // tile 0 DMA drained
    for (int k0 = 0; k0 < K; k0 += 2 * BKK) {
        if (k0 + BKK < K) stage(As1, Bs1, k0 + BKK);
        compute(As0, Bs0);
        __syncthreads();
        if (k0 + 2 * BKK < K) stage(As0, Bs0, k0 + 2 * BKK);
        compute(As1, Bs1);
        __syncthreads();
    }

    int rq = quad * 4;
    int cq = fr;
    for (int i = 0; i < 4; ++i)
        for (int j = 0; j < 4; ++j)
            for (int reg = 0; reg < 4; ++reg) {
                int row = row0 + wm + i * 16 + rq + reg;
                int col = col0 + j * 16 + cq;
                C[(size_t)row * DM + col] = acc[i][j][reg];
            }
}

// ---------------- RoPE in place on K only (R28) ----------------
// Q-rope lives in k_attn's Q-load prologue. K rows are staged by many attn
// blocks each, so K-rope stays standalone. 2048 blocks.
__global__ void k_rope(unsigned short* __restrict__ kbuf,
                       const float* __restrict__ cosb, const float* __restrict__ sinb) {
    int t = blockIdx.x * 256 + threadIdx.x;
    int c = t & 7;
    int row = t >> 3;                  // 0..65535
    unsigned short* p = kbuf + (size_t)row * HD + c * 8;
    int s = row & (SEQ - 1);
    const float* cs = cosb + s * 32 + c * 4;
    const float* sn = sinb + s * 32 + c * 4;
    bf16x8 v = *(const bf16x8*)p;
    bf16x8 o;
    for (int i = 0; i < 4; ++i) {
        float x1 = bf2f((unsigned short)v[2 * i]);
        float x2 = bf2f((unsigned short)v[2 * i + 1]);
        float cc = cs[i], ss = sn[i];
        o[2 * i]     = (short)f2bf(x1 * cc - x2 * ss);
        o[2 * i + 1] = (short)f2bf(x1 * ss + x2 * cc);
    }
    *(bf16x8*)p = o;
}

// ---------------- Flash attention: causal work-paired, 4-wave blocks (FINAL) --
// R29: 4 waves (256 threads) per block, grid (16,32). Each wave owns TWO
// complementary 16-query sets: low tile (4p+w), high tile (127-4p-w) --
// bijection onto all 128 q16-tiles, per-wave causal work ~33 set-tiles. Each
// 16KB K/V staging serves 8 query sets -> staging traffic halved vs 2-wave.
// 2 blocks/CU x 4 waves = 8 waves/CU. Q-rope + softmax_scale*log2(e) applied
// in-register at Q-frag load (R28; prologue-only, no loop-carried state).
// R30 XCD remap REVERTED (R15: neutral-to-negative -- K/V re-reads were
// already L3-absorbed; the pipeline hides L3-hit latency).
// NOTE (R11): no setprio -- barrier-lockstep waves (m190 regime).
__global__ void __launch_bounds__(256, 2) k_attn(const unsigned short* __restrict__ qbuf,
                                                 const unsigned short* __restrict__ kbuf,
                                                 const unsigned short* __restrict__ vt,
                                                 const float* __restrict__ cosb,
                                                 const float* __restrict__ sinb,
                                                 unsigned short* __restrict__ obuf) {
    __shared__ unsigned short Ks0[64 * 64];
    __shared__ unsigned short Ks1[64 * 64];
    __shared__ unsigned short Vs0[64 * 64];
    __shared__ unsigned short Vs1[64 * 64];

    int tid = threadIdx.x;             // 0..255
    int lane = tid & 63, wave = tid >> 6;  // wave 0..3
    int bh = blockIdx.y;
    int b = bh >> 4, h = bh & 15;
    int p = ((int)blockIdx.x + (int)blockIdx.y) & 15;  // swizzled pair index
    int fr = lane & 15, quad = lane >> 4, sw = fr & 7;
    // This wave's two 16-query sets: low tile (4p+w), high tile (127-4p-w).
    int Qb0 = (4 * p + wave) * 16;
    int Qb1 = (127 - 4 * p - wave) * 16;
    // Block-uniform trip count: covers the widest causal range in the block.
    int KT = ((127 - 4 * p) >> 2) + 1;

    const unsigned short* Qb = qbuf + (size_t)bh * SEQ * HD;
    const unsigned short* Kb = kbuf + (size_t)bh * SEQ * HD;
    const unsigned short* Vb = vt + (size_t)bh * HD * SEQ;

    // Q B-frags, 2 sets of 16 queries. RoPE + 1/sqrt(64)*log2(e) pre-scale
    // applied in-register (R28); pair idx = d/2, frag covers d = dbase..+7.
    auto ropeQ = [&](bf16x8 v, int qrow, int dbase) -> bf16x8 {
        const float sc = 0.125f * 1.44269504f;
        const float* cs = cosb + (size_t)qrow * 32 + (dbase >> 1);
        const float* sn = sinb + (size_t)qrow * 32 + (dbase >> 1);
        bf16x8 o;
        for (int i = 0; i < 4; ++i) {
            float x1 = bf2f((unsigned short)v[2 * i]);
            float x2 = bf2f((unsigned short)v[2 * i + 1]);
            float cc = cs[i], ss = sn[i];
            o[2 * i]     = (short)f2bf((x1 * cc - x2 * ss) * sc);
            o[2 * i + 1] = (short)f2bf((x1 * ss + x2 * cc) * sc);
        }
        return o;
    };
    bf16x8 qf[2][2];
    for (int s = 0; s < 2; ++s) {
        int qrow = (s ? Qb1 : Qb0) + fr;   // within [0, SEQ)
        qf[s][0] = ropeQ(*(const bf16x8*)(Qb + (size_t)qrow * HD + quad * 8), qrow, quad * 8);
        qf[s][1] = ropeQ(*(const bf16x8*)(Qb + (size_t)qrow * HD + 32 + quad * 8), qrow, 32 + quad * 8);
    }

    f32x4 zero4 = {0.f, 0.f, 0.f, 0.f};
    f32x4 o[2][4];
    for (int s = 0; s < 2; ++s)
        for (int j = 0; j < 4; ++j) o[s][j] = zero4;
    float l[2] = {0.f, 0.f};

    // DMA staging (256 threads): 512 16B-slots per K tile -> 2 issues each.
    auto stage = [&](int kb, unsigned short* Kd, unsigned short* Vd) {
        for (int a = 0; a < 2; ++a) {
            int idx = a * 256 + tid;
            int r = idx >> 3;
            int lg = (idx & 7) ^ (r & 7);
            gld_lds16(Kb + (size_t)(kb + r) * HD + lg * 8, Kd + (a * 256 + wave * 64) * 8);
            gld_lds16(Vb + (size_t)r * SEQ + kb + lg * 8, Vd + (a * 256 + wave * 64) * 8);
        }
    };

    auto compute = [&](int kt, const unsigned short* Kd, const unsigned short* Vd) {
        int kb = kt * 64;
        // ---- fragments once per tile, shared by both query sets ----
        bf16x8 ka[4], kc[4];
        for (int g = 0; g < 4; ++g) {
            int r = g * 16 + fr;
            ka[g] = *(const bf16x8*)&Kd[r * 64 + ((quad ^ sw) * 8)];
            kc[g] = *(const bf16x8*)&Kd[r * 64 + (((quad + 4) ^ sw) * 8)];
        }
        bf16x4 vf[4][4];
        for (int g = 0; g < 4; ++g)
            for (int db = 0; db < 4; ++db) {
                int d = db * 16 + fr;
                int pg = ((2 * g + (quad >> 1)) ^ sw) * 8 + (quad & 1) * 4;
                vf[g][db] = *(const bf16x4*)&Vd[d * 64 + pg];
            }
        // ---- two 16-query sets through QK -> softmax -> PV ----
        for (int s = 0; s < 2; ++s) {
            int Qs = s ? Qb1 : Qb0;
            if (kb > Qs + 15) continue;  // set fully below this K-tile: skip (wave-uniform)
            f32x4 sg[4];
            for (int g = 0; g < 4; ++g) {
                f32x4 z = zero4;
                z = __builtin_amdgcn_mfma_f32_16x16x32_bf16(ka[g], qf[s][0], z, 0, 0, 0);
                z = __builtin_amdgcn_mfma_f32_16x16x32_bf16(kc[g], qf[s][1], z, 0, 0, 0);
                sg[g] = z;
            }
            if (kb + 63 > Qs) {  // any key could exceed the smallest query
                int q = Qs + fr;
                for (int g = 0; g < 4; ++g)
                    for (int reg = 0; reg < 4; ++reg)
                        if (kb + g * 16 + quad * 4 + reg > q) sg[g][reg] = -1e30f;
            }
            bf16x4 pf[4];
            for (int g = 0; g < 4; ++g) {
                float p0 = fexp2(sg[g][0]);
                float p1 = fexp2(sg[g][1]);
                float p2 = fexp2(sg[g][2]);
                float p3 = fexp2(sg[g][3]);
                l[s] += (p0 + p1) + (p2 + p3);
                union { bf16x4 v; unsigned u[2]; } pc;
                pc.u[0] = pkbf16(p0, p1);
                pc.u[1] = pkbf16(p2, p3);
                pf[g] = pc.v;
            }
            for (int g = 0; g < 4; ++g)
                for (int db = 0; db < 4; ++db)
                    o[s][db] = mfma16(pf[g], vf[g][db], o[s][db]);
        }
    };

    stage(0, Ks0, Vs0);
    __syncthreads();  // tile 0 DMA drained
    for (int kt = 0; kt < KT; kt += 2) {
        if (kt + 1 < KT) stage((kt + 1) * 64, Ks1, Vs1);
        compute(kt, Ks0, Vs0);
        __syncthreads();  // Ks0/Vs0 readers done; Ks1/Vs1 DMA drained
        if (kt + 1 < KT) {
            if (kt + 2 < KT) stage((kt + 2) * 64, Ks0, Vs0);
            compute(kt + 1, Ks1, Vs1);
            __syncthreads();
        }
    }

    // ---- per set: finish l across quads; store ----
    for (int s = 0; s < 2; ++s) {
        float ll = l[s];
        ll += __shfl_xor(ll, 16);
        ll += __shfl_xor(ll, 32);
        float linv[4];
        for (int reg = 0; reg < 4; ++reg)
            linv[reg] = frcp(__shfl(ll, quad * 4 + reg));
        int Qs = s ? Qb1 : Qb0;
        for (int db = 0; db < 4; ++db)
            for (int reg = 0; reg < 4; ++reg) {
                int row = Qs + quad * 4 + reg;
                int d = db * 16 + fr;
                obuf[((size_t)(b * SEQ + row)) * DM + h * HD + d] = f2bf(o[s][db][reg] * linv[reg]);
            }
    }
}

extern "C" void kernel_launch(void* const* d_in, const int* in_sizes, int n_in,
                              void* d_out, int out_size, void* d_ws, size_t ws_size,
                              hipStream_t stream) {
    const float* x    = (const float*)d_in[0];
    const float* rc   = (const float*)d_in[1];
    const float* rs   = (const float*)d_in[2];
    const float* wqkv = (const float*)d_in[3];
    const float* wout = (const float*)d_in[4];
    float* out = (float*)d_out;

    char* ws = (char*)d_ws;
    size_t off = 0;
    auto alloc = [&](size_t bytes) {
        char* p = ws + off;
        off += (bytes + 255) & ~(size_t)255;
        return p;
    };
    unsigned short* xb    = (unsigned short*)alloc((size_t)TOK * DM * 2);
    unsigned short* wqkvt = (unsigned short*)alloc((size_t)3 * DM * DM * 2);
    unsigned short* woutt = (unsigned short*)alloc((size_t)DM * DM * 2);
    unsigned short* qbuf  = (unsigned short*)alloc((size_t)BATCH * NH * SEQ * HD * 2);
    unsigned short* kbuf  = (unsigned short*)alloc((size_t)BATCH * NH * SEQ * HD * 2);
    unsigned short* vtb   = (unsigned short*)alloc((size_t)BATCH * NH * SEQ * HD * 2);
    unsigned short* obuf  = (unsigned short*)alloc((size_t)TOK * DM * 2);

    k_prep<<<5120, 256, 0, stream>>>(x, xb, wqkv, wqkvt, wout, woutt);
    k_gemm_qkv<<<dim3(3 * DM / 128, TOK / 128), 256, 0, stream>>>(xb, wqkvt, qbuf, kbuf, vtb);
    k_rope<<<2048, 256, 0, stream>>>(kbuf, rc, rs);
    k_attn<<<dim3(SEQ / 128, BATCH * NH), 256, 0, stream>>>(qbuf, kbuf, vtb, rc, rs, obuf);
    k_gemm_out<<<dim3(DM / 64, TOK / 128), 128, 0, stream>>>(obuf, woutt, out);
}